// Round 8
// baseline (441.966 us; speedup 1.0000x reference)
//
#include <hip/hip_runtime.h>

// (B,T,D,H,KD)=(8,1024,512,8,64), SIGMA=1.
// d_out: out [8*1024*512] f32, then attn_weights [64][1024][1024] f32.
// R12: GEMM tile 64x64 -> 128x64 (BM=128), all four GEMMs.  Per K-step per
// wave: MFMAs 4->8, barriers halved per output element (learn_hip m93:
// 64->128 tile = 1.51x).  grid 1024->512 (2 blocks/CU, 8 waves/CU).
// LDS: proj 40KB, out 24KB.  Flash + wt_cvt unchanged from R11 (f16
// pipeline, attn @2^60 scale, q2/k2 from f16-rounded projections).

typedef float  floatx4 __attribute__((ext_vector_type(4)));
typedef _Float16 half8 __attribute__((ext_vector_type(8)));
typedef unsigned short ushort_t;

#define MFMA16F(a, b, c) __builtin_amdgcn_mfma_f32_16x16x32_f16((a), (b), (c), 0, 0, 0)

#define P_SCALE   0x1p60f
#define P_ISCALE  0x1p-60f

// Async global->LDS, 16B per lane.  LDS dest = wave-uniform base + lane*16.
__device__ inline void gl_lds16(const void* g, void* l) {
    __builtin_amdgcn_global_load_lds(
        (const __attribute__((address_space(1))) unsigned int*)g,
        (__attribute__((address_space(3))) unsigned int*)l, 16, 0, 0);
}

// ---------------------------------------------------------------------------
// Weight transpose via LDS tile (coalesced both sides): WT[n][k] = f16(W[k][n]).
// grid (64 tiles, 4 weights), 256 threads; tile = 64(k) x 64(n).
// ---------------------------------------------------------------------------
__global__ __launch_bounds__(256) void wt_cvt(
    const float* __restrict__ Wq, const float* __restrict__ Wk,
    const float* __restrict__ Wv, const float* __restrict__ Wo,
    ushort_t* __restrict__ qT, ushort_t* __restrict__ kT,
    ushort_t* __restrict__ vT, ushort_t* __restrict__ oT)
{
    __shared__ float sT[64][65];
    const int tid = threadIdx.x;
    const int c = tid & 63, rq = tid >> 6;
    const int bx = blockIdx.x;
    const int k0 = (bx >> 3) * 64, n0 = (bx & 7) * 64;

    const float* W; ushort_t* H;
    switch (blockIdx.y) {
        case 0:  W = Wq; H = qT; break;
        case 1:  W = Wk; H = kT; break;
        case 2:  W = Wv; H = vT; break;
        default: W = Wo; H = oT; break;
    }

#pragma unroll
    for (int i = 0; i < 16; ++i) {
        const int row = i * 4 + rq;                      // k within tile
        sT[row][c] = W[(size_t)(k0 + row) * 512 + n0 + c];
    }
    __syncthreads();
#pragma unroll
    for (int i = 0; i < 16; ++i) {
        const int nrow = i * 4 + rq;                     // n within tile
        ((_Float16*)H)[(size_t)(n0 + nrow) * 512 + k0 + c] = (_Float16)sT[c][nrow];
    }
}

// ---------------------------------------------------------------------------
// LDS-staged f16 MFMA GEMM, K=512, tile 128x64, BK=32, 256 threads (4 waves,
// wave w owns rows 32w..32w+31 x all 64 cols; acc[2][4]).  grid = 512:
// mt=gid>>3 (128-row tile), nt=gid&7 (n-panel -> per-XCD B locality).
// 2-phase prefetch: double-buffered LDS, stage(it+1) issued before
// compute(it), single barrier/iter.  B always f16.
// AF32 true: A fp32 staged raw (16KB/tile), f16 cast after LDS read.
// AF32 false: A f16 staged directly (8KB/tile).  8 MFMAs per wave per iter.
// OUTMODE 0: out f32 = acc * 2^-60 (A carries the 2^60 P scale).
// OUTMODE 1: f16 + fused row-norms from the ROUNDED value -> normOut[z][t]
// (64-col n-panel = one head; flash then sees exact ||q~-k~||^2).
// OUTMODE 2: vhT[z][d][T] f16.
// Chunk swizzle: LDS slot = (chunk + row) % nchunks -> conflict-free reads.
// ---------------------------------------------------------------------------
template <bool AF32, int OUTMODE>
__global__ __launch_bounds__(256) void gemm_f16(
    const void* __restrict__ A, const ushort_t* __restrict__ BT,
    float* __restrict__ outF, ushort_t* __restrict__ outH,
    float* __restrict__ normOut)
{
    __shared__ __align__(16) float    sAf[AF32 ? 2 * 128 * 32 : 4];   // fp32 A dbuf
    __shared__ __align__(16) ushort_t sAh[AF32 ? 8 : 2 * 128 * 32];   // f16 A dbuf
    __shared__ __align__(16) ushort_t sB [2 * 64 * 32];               // f16 B dbuf

    const int tid = threadIdx.x;
    const int w = tid >> 6, lane = tid & 63;
    const int l15 = lane & 15, quad = lane >> 4;
    const int gid = blockIdx.x;
    const int m0 = (gid >> 3) * 128, n0 = (gid & 7) * 64;

    auto STAGE = [&](int bi, int it) {
        const int k0 = it * 32;
        if constexpr (AF32) {
            // A tile 128x32 f32 = 16KB: 1024 chunks, rows of 8, swizzled.
#pragma unroll
            for (int t = 0; t < 4; ++t) {
                const int c = (w * 4 + t) * 64 + lane;
                const int row = c >> 3, slot = c & 7, kch = (slot - row) & 7;
                gl_lds16((const float*)A + (size_t)(m0 + row) * 512 + k0 + kch * 4,
                         (char*)sAf + (size_t)bi * 16384 + (size_t)(w * 4 + t) * 1024);
            }
        } else {
            // A tile 128x32 f16 = 8KB: 512 chunks, rows of 4, swizzled.
#pragma unroll
            for (int t = 0; t < 2; ++t) {
                const int c = (w * 2 + t) * 64 + lane;
                const int row = c >> 2, slot = c & 3, kch = (slot - row) & 3;
                gl_lds16((const ushort_t*)A + (size_t)(m0 + row) * 512 + k0 + kch * 8,
                         (char*)sAh + (size_t)bi * 8192 + (size_t)(w * 2 + t) * 1024);
            }
        }
        {
            const int c = w * 64 + lane;
            const int row = c >> 2, slot = c & 3, kch = (slot - row) & 3;
            gl_lds16(BT + (size_t)(n0 + row) * 512 + k0 + kch * 8,
                     (char*)sB + (size_t)bi * 4096 + (size_t)w * 1024);
        }
    };

    floatx4 acc[2][4];
#pragma unroll
    for (int mi = 0; mi < 2; ++mi)
#pragma unroll
        for (int ni = 0; ni < 4; ++ni) acc[mi][ni] = (floatx4){0.f, 0.f, 0.f, 0.f};

    STAGE(0, 0);
    __syncthreads();
    int cur = 0;

    for (int it = 0; it < 16; ++it) {
        if (it + 1 < 16) STAGE(cur ^ 1, it + 1);   // prefetch, drains at barrier

        const float*    Af = sAf + (size_t)cur * (AF32 ? 128 * 32 : 0);
        const ushort_t* Ah = sAh + (size_t)cur * (AF32 ? 0 : 128 * 32);
        const ushort_t* Bb = sB  + (size_t)cur * (64 * 32);

        // ---- A fragments (2 row-tiles per wave) ----
        half8 ah[2];
#pragma unroll
        for (int mi = 0; mi < 2; ++mi) {
            const int row = 32 * w + 16 * mi + l15;
            if constexpr (AF32) {
                float4 f0 = *(const float4*)&Af[row * 32 + ((quad * 2 + row) & 7) * 4];
                float4 f1 = *(const float4*)&Af[row * 32 + ((quad * 2 + 1 + row) & 7) * 4];
                ah[mi][0] = (_Float16)f0.x; ah[mi][1] = (_Float16)f0.y;
                ah[mi][2] = (_Float16)f0.z; ah[mi][3] = (_Float16)f0.w;
                ah[mi][4] = (_Float16)f1.x; ah[mi][5] = (_Float16)f1.y;
                ah[mi][6] = (_Float16)f1.z; ah[mi][7] = (_Float16)f1.w;
            } else {
                ah[mi] = *(const half8*)&Ah[row * 32 + ((quad + row) & 3) * 8];
            }
        }
        half8 bh[4];
#pragma unroll
        for (int ni = 0; ni < 4; ++ni) {
            const int row = ni * 16 + l15;
            bh[ni] = *(const half8*)&Bb[row * 32 + ((quad + row) & 3) * 8];
        }
        // ---- MFMAs (8 per wave per iter) ----
#pragma unroll
        for (int mi = 0; mi < 2; ++mi)
#pragma unroll
            for (int ni = 0; ni < 4; ++ni)
                acc[mi][ni] = MFMA16F(ah[mi], bh[ni], acc[mi][ni]);
        __syncthreads();
        cur ^= 1;
    }

    // ---- epilogue ----
#pragma unroll
    for (int mi = 0; mi < 2; ++mi) {
#pragma unroll
        for (int ni = 0; ni < 4; ++ni) {
            const int n = n0 + ni * 16 + l15;
#pragma unroll
            for (int r = 0; r < 4; ++r) {
                const int m = m0 + 32 * w + 16 * mi + quad * 4 + r;
                const float v = acc[mi][ni][r];
                if (OUTMODE == 0) {
                    outF[(size_t)m * 512 + n] = v * P_ISCALE;
                } else if (OUTMODE == 1) {
                    ((_Float16*)outH)[(size_t)m * 512 + n] = (_Float16)v;
                } else {
                    const int b = m >> 10, t = m & 1023, hh = n >> 6, d = n & 63;
                    ((_Float16*)outH)[((size_t)(b * 8 + hh) * 64 + d) * 1024 + t] =
                        (_Float16)v;
                }
            }
        }
        if (OUTMODE == 1) {
            // Fused per-head squared norms from the f16-ROUNDED values (must
            // match what flash reads for exact ||q~-k~||^2 expansion).
#pragma unroll
            for (int r = 0; r < 4; ++r) {
                float s2 = 0.f;
#pragma unroll
                for (int ni = 0; ni < 4; ++ni) {
                    const float rv = (float)(_Float16)acc[mi][ni][r];
                    s2 = fmaf(rv, rv, s2);
                }
#pragma unroll
                for (int off = 1; off < 16; off <<= 1) s2 += __shfl_xor(s2, off);
                if (l15 == 0) {
                    const int m = m0 + 32 * w + 16 * mi + quad * 4 + r;
                    normOut[(size_t)((m >> 10) * 8 + (gid & 7)) * 1024 + (m & 1023)] = s2;
                }
            }
        }
    }
}

// ---------------------------------------------------------------------------
// Fused flash (R11, unchanged): block = (z, 64 q-rows), 4 waves;
// gid = qt*64+z so gid%8==h (XCD L2 locality for K/V).  Per 64-col tile:
// stage K/V^T f16 (2x8KB, swizzled) -> barrier -> QK 1-pass f16 MFMA ->
// exp -> S store + P strip (f16, x2^60) -> SV f16 MFMA -> barrier.
// 25.2KB LDS -> 4+ blocks/CU.  attn stored f16 AT the 2^60 scale.
// ---------------------------------------------------------------------------
__global__ __launch_bounds__(256) void flash_rbf(
    const ushort_t* __restrict__ qh, const ushort_t* __restrict__ kh,
    const ushort_t* __restrict__ vhT, const float* __restrict__ q2,
    const float* __restrict__ k2, float* __restrict__ S,
    ushort_t* __restrict__ attn)
{
    __shared__ __align__(16) ushort_t sK[64 * 64];
    __shared__ __align__(16) ushort_t sV[64 * 64];
    __shared__ __align__(16) ushort_t P [64 * 72];

    const int tid = threadIdx.x;
    const int w = tid >> 6, lane = tid & 63;
    const int l15 = lane & 15, quad = lane >> 4;
    const int gid = blockIdx.x;
    const int z = gid & 63, qt = gid >> 6;
    const int b = z >> 3, h = z & 7;
    const int q0 = qt * 64;

    // Q fragments (f16 registers, whole block).
    const size_t qrow = (size_t)(b * 1024 + q0 + 16 * w + l15) * 512 + h * 64 + quad * 8;
    half8 aq0 = *(const half8*)((const _Float16*)qh + qrow);
    half8 aq1 = *(const half8*)((const _Float16*)qh + qrow + 32);

    float q2v[4];
#pragma unroll
    for (int r = 0; r < 4; ++r)
        q2v[r] = q2[(size_t)z * 1024 + q0 + 16 * w + quad * 4 + r];

    floatx4 oacc[4];
#pragma unroll
    for (int i = 0; i < 4; ++i) oacc[i] = (floatx4){0.f, 0.f, 0.f, 0.f};

    const size_t Sz = (size_t)z << 20;

    for (int ct = 0; ct < 16; ++ct) {
        const int col0 = ct * 64;

        // ---- stage K + V^T f16 tiles (rows of 8 chunks, swizzled) ----
#pragma unroll
        for (int t = 0; t < 2; ++t) {
            const int c = (w * 2 + t) * 64 + lane;
            const int row = c >> 3, slot = c & 7, dch = (slot - row) & 7;
            const size_t ke = (size_t)(b * 1024 + col0 + row) * 512 + h * 64 + dch * 8;
            const size_t ve = ((size_t)z * 64 + row) * 1024 + col0 + dch * 8;
            gl_lds16(kh + ke,  (char*)sK + (size_t)(w * 2 + t) * 1024);
            gl_lds16(vhT + ve, (char*)sV + (size_t)(w * 2 + t) * 1024);
        }
        float k2v[4];
#pragma unroll
        for (int j = 0; j < 4; ++j)
            k2v[j] = k2[(size_t)z * 1024 + col0 + j * 16 + l15];
        __syncthreads();

        // ---- QK^T, 1-pass f16 ----
        floatx4 s[4];
#pragma unroll
        for (int j = 0; j < 4; ++j) {
            const int row = j * 16 + l15;
            const int base = row * 64;
            half8 k0 = *(const half8*)&sK[base + ((quad + row) & 7) * 8];
            half8 k1 = *(const half8*)&sK[base + ((quad + 4 + row) & 7) * 8];
            s[j] = (floatx4){0.f, 0.f, 0.f, 0.f};
            s[j] = MFMA16F(aq0, k0, s[j]);
            s[j] = MFMA16F(aq1, k1, s[j]);
        }

        // ---- V fragments (f16) ----
        half8 gv0[4], gv1[4];
#pragma unroll
        for (int j2 = 0; j2 < 4; ++j2) {
            const int row = j2 * 16 + l15;
            const int base = row * 64;
            gv0[j2] = *(const half8*)&sV[base + ((quad + row) & 7) * 8];
            gv1[j2] = *(const half8*)&sV[base + ((quad + 4 + row) & 7) * 8];
        }

        // ---- exp, S store, P pack (f16, scaled 2^60) ----
#pragma unroll
        for (int j = 0; j < 4; ++j) {
#pragma unroll
            for (int r = 0; r < 4; ++r) {
                const float val = __expf(2.f * s[j][r] - q2v[r] - k2v[j]);
                const int row = q0 + 16 * w + quad * 4 + r;
                S[Sz + (size_t)row * 1024 + col0 + j * 16 + l15] = val;
                P[(16 * w + quad * 4 + r) * 72 + j * 16 + l15] =
                    __builtin_bit_cast(ushort_t, (_Float16)(val * P_SCALE));
            }
        }

        // ---- P readback (A-layout, wave-local) + S@V, f16 ----
        half8 pf0 = *(const half8*)&P[(16 * w + l15) * 72 + quad * 8];
        half8 pf1 = *(const half8*)&P[(16 * w + l15) * 72 + 32 + quad * 8];
#pragma unroll
        for (int j2 = 0; j2 < 4; ++j2) {
            oacc[j2] = MFMA16F(pf0, gv0[j2], oacc[j2]);
            oacc[j2] = MFMA16F(pf1, gv1[j2], oacc[j2]);
        }
        __syncthreads();
    }

    // attn stored f16 at the 2^60 scale (out GEMM applies 2^-60).
#pragma unroll
    for (int j2 = 0; j2 < 4; ++j2)
#pragma unroll
        for (int r = 0; r < 4; ++r) {
            const int row = q0 + 16 * w + quad * 4 + r;
            ((_Float16*)attn)[(size_t)(b * 1024 + row) * 512 + h * 64 + j2 * 16 + l15] =
                (_Float16)oacc[j2][r];
        }
}

extern "C" void kernel_launch(void* const* d_in, const int* in_sizes, int n_in,
                              void* d_out, int out_size, void* d_ws, size_t ws_size,
                              hipStream_t stream)
{
    const float* query = (const float*)d_in[0];
    const float* key   = (const float*)d_in[1];
    const float* value = (const float*)d_in[2];
    const float* Wq    = (const float*)d_in[3];
    const float* Wk    = (const float*)d_in[4];
    const float* Wv    = (const float*)d_in[5];
    const float* Wo    = (const float*)d_in[6];

    float* out  = (float*)d_out;
    float* Sout = out + (size_t)8192 * 512;

    const size_t NE = (size_t)8192 * 512;
    ushort_t* qh_f16   = (ushort_t*)d_ws;
    ushort_t* kh_f16   = qh_f16 + NE;
    ushort_t* vhT      = kh_f16 + NE;
    ushort_t* attn_f16 = vhT + NE;
    ushort_t* WqT      = attn_f16 + NE;
    ushort_t* WkT      = WqT + 262144;
    ushort_t* WvT      = WkT + 262144;
    ushort_t* WoT      = WvT + 262144;
    float*    q2       = (float*)(WoT + 262144);
    float*    k2       = q2 + 65536;

    wt_cvt<<<dim3(64, 4), 256, 0, stream>>>(Wq, Wk, Wv, Wo, WqT, WkT, WvT, WoT);

    gemm_f16<true, 1><<<512, 256, 0, stream>>>(
        query, WqT, nullptr, qh_f16, q2);
    gemm_f16<true, 1><<<512, 256, 0, stream>>>(
        key, WkT, nullptr, kh_f16, k2);
    gemm_f16<true, 2><<<512, 256, 0, stream>>>(
        value, WvT, nullptr, vhT, nullptr);

    flash_rbf<<<1024, 256, 0, stream>>>(qh_f16, kh_f16, vhT, q2, k2,
                                        Sout, attn_f16);

    gemm_f16<false, 0><<<512, 256, 0, stream>>>(
        attn_f16, WoT, out, nullptr, nullptr);
}

// Round 9
// 411.025 us; speedup vs baseline: 1.0753x; 1.0753x over previous
//
#include <hip/hip_runtime.h>

// (B,T,D,H,KD)=(8,1024,512,8,64), SIGMA=1.
// d_out: out [8*1024*512] f32, then attn_weights [64][1024][1024] f32.
// R13: R11 (best, 430.7us) + XCD-aware GEMM grid remap.  Old mapping
// (gid%8 = n-panel) scattered the 8 blocks sharing an A m-tile across all
// 8 XCDs -> A (16MB/proj) re-fetched 8x via L3 while "protecting" B (0.5MB,
// L2-trivial anywhere).  New: gid -> (xcd=gid&7, mtl=(gid>>3)&15, nt=gid>>7),
// mt = xcd*16+mtl: per-XCD A = 2MB -> L2-resident, fetched once from HBM.
// Accumulation order unchanged -> absmax bit-identical.  Tiles stay 64x64
// (R12 proved 128-tiles lose: these GEMMs are concurrency-bound).
// Flash unchanged (same-z -> same-XCD already holds).

typedef float  floatx4 __attribute__((ext_vector_type(4)));
typedef _Float16 half8 __attribute__((ext_vector_type(8)));
typedef unsigned short ushort_t;

#define MFMA16F(a, b, c) __builtin_amdgcn_mfma_f32_16x16x32_f16((a), (b), (c), 0, 0, 0)

#define P_SCALE   0x1p60f
#define P_ISCALE  0x1p-60f

// Async global->LDS, 16B per lane.  LDS dest = wave-uniform base + lane*16.
__device__ inline void gl_lds16(const void* g, void* l) {
    __builtin_amdgcn_global_load_lds(
        (const __attribute__((address_space(1))) unsigned int*)g,
        (__attribute__((address_space(3))) unsigned int*)l, 16, 0, 0);
}

// ---------------------------------------------------------------------------
// Weight transpose via LDS tile (coalesced both sides): WT[n][k] = f16(W[k][n]).
// grid (64 tiles, 4 weights), 256 threads; tile = 64(k) x 64(n).
// ---------------------------------------------------------------------------
__global__ __launch_bounds__(256) void wt_cvt(
    const float* __restrict__ Wq, const float* __restrict__ Wk,
    const float* __restrict__ Wv, const float* __restrict__ Wo,
    ushort_t* __restrict__ qT, ushort_t* __restrict__ kT,
    ushort_t* __restrict__ vT, ushort_t* __restrict__ oT)
{
    __shared__ float sT[64][65];
    const int tid = threadIdx.x;
    const int c = tid & 63, rq = tid >> 6;
    const int bx = blockIdx.x;
    const int k0 = (bx >> 3) * 64, n0 = (bx & 7) * 64;

    const float* W; ushort_t* H;
    switch (blockIdx.y) {
        case 0:  W = Wq; H = qT; break;
        case 1:  W = Wk; H = kT; break;
        case 2:  W = Wv; H = vT; break;
        default: W = Wo; H = oT; break;
    }

#pragma unroll
    for (int i = 0; i < 16; ++i) {
        const int row = i * 4 + rq;                      // k within tile
        sT[row][c] = W[(size_t)(k0 + row) * 512 + n0 + c];
    }
    __syncthreads();
#pragma unroll
    for (int i = 0; i < 16; ++i) {
        const int nrow = i * 4 + rq;                     // n within tile
        ((_Float16*)H)[(size_t)(n0 + nrow) * 512 + k0 + c] = (_Float16)sT[c][nrow];
    }
}

// ---------------------------------------------------------------------------
// LDS-staged f16 MFMA GEMM, K=512, tile 64x64, BK=32, 256 threads (4 waves,
// wave w owns rows 16w..16w+15 x all 64 cols).  grid = 1024.
// XCD remap: xcd=gid&7, mtl=(gid>>3)&15, nt=gid>>7; mt=xcd*16+mtl.
// All 8 n-panels of an m-tile run on ONE XCD -> A tile L2-resident (2MB
// fp32 / 1MB f16 per XCD), fetched once from HBM.  B panels 512KB/XCD.
// 2-phase prefetch: double-buffered LDS, stage(it+1) issued before
// compute(it), single barrier/iter.  B always f16.
// AF32 true: A fp32 staged raw, f16 cast after LDS read.
// AF32 false: A f16 staged directly.  1 MFMA per ni per iter.
// OUTMODE 0: out f32 = acc * 2^-60 (A carries the 2^60 P scale).
// OUTMODE 1: f16 + fused row-norms from the ROUNDED value -> normOut[z][t]
// (64-col n-panel = one head = nt; flash then sees exact ||q~-k~||^2).
// OUTMODE 2: vhT[z][d][T] f16.
// Chunk swizzle: LDS slot = (chunk + row) % nchunks -> conflict-free reads.
// ---------------------------------------------------------------------------
template <bool AF32, int OUTMODE>
__global__ __launch_bounds__(256) void gemm_f16(
    const void* __restrict__ A, const ushort_t* __restrict__ BT,
    float* __restrict__ outF, ushort_t* __restrict__ outH,
    float* __restrict__ normOut)
{
    __shared__ __align__(16) float    sAf[AF32 ? 2 * 64 * 32 : 4];   // fp32 A dbuf
    __shared__ __align__(16) ushort_t sAh[AF32 ? 8 : 2 * 64 * 32];   // f16 A dbuf
    __shared__ __align__(16) ushort_t sB [2 * 64 * 32];              // f16 B dbuf

    const int tid = threadIdx.x;
    const int w = tid >> 6, lane = tid & 63;
    const int l15 = lane & 15, quad = lane >> 4;
    const int gid = blockIdx.x;
    // XCD-aware remap: same m-tile -> same XCD (A L2-reuse across n-panels).
    const int xcd = gid & 7, mtl = (gid >> 3) & 15, nt = gid >> 7;
    const int m0 = (xcd * 16 + mtl) * 64, n0 = nt * 64;

    auto STAGE = [&](int bi, int it) {
        const int k0 = it * 32;
        if constexpr (AF32) {
            // A tile 64x32 f32 = 8KB: rows of 8 chunks, swizzled.
#pragma unroll
            for (int t = 0; t < 2; ++t) {
                const int c = (w * 2 + t) * 64 + lane;
                const int row = c >> 3, slot = c & 7, kch = (slot - row) & 7;
                gl_lds16((const float*)A + (size_t)(m0 + row) * 512 + k0 + kch * 4,
                         (char*)sAf + (size_t)bi * 8192 + (size_t)(w * 2 + t) * 1024);
            }
        } else {
            // A tile 64x32 f16 = 4KB: rows of 4 chunks.
            const int c = w * 64 + lane;
            const int row = c >> 2, slot = c & 3, kch = (slot - row) & 3;
            gl_lds16((const ushort_t*)A + (size_t)(m0 + row) * 512 + k0 + kch * 8,
                     (char*)sAh + (size_t)bi * 4096 + (size_t)w * 1024);
        }
        {
            const int c = w * 64 + lane;
            const int row = c >> 2, slot = c & 3, kch = (slot - row) & 3;
            gl_lds16(BT + (size_t)(n0 + row) * 512 + k0 + kch * 8,
                     (char*)sB + (size_t)bi * 4096 + (size_t)w * 1024);
        }
    };

    floatx4 acc[4];
#pragma unroll
    for (int i = 0; i < 4; ++i) acc[i] = (floatx4){0.f, 0.f, 0.f, 0.f};

    STAGE(0, 0);
    __syncthreads();
    int cur = 0;

    for (int it = 0; it < 16; ++it) {
        if (it + 1 < 16) STAGE(cur ^ 1, it + 1);   // prefetch, drains at barrier

        const float*    Af = sAf + (size_t)cur * (AF32 ? 64 * 32 : 0);
        const ushort_t* Ah = sAh + (size_t)cur * (AF32 ? 0 : 64 * 32);
        const ushort_t* Bb = sB  + (size_t)cur * (64 * 32);

        // ---- fragments ----
        half8 ah;
        {
            const int row = 16 * w + l15;
            if constexpr (AF32) {
                float4 f0 = *(const float4*)&Af[row * 32 + ((quad * 2 + row) & 7) * 4];
                float4 f1 = *(const float4*)&Af[row * 32 + ((quad * 2 + 1 + row) & 7) * 4];
                ah[0] = (_Float16)f0.x; ah[1] = (_Float16)f0.y;
                ah[2] = (_Float16)f0.z; ah[3] = (_Float16)f0.w;
                ah[4] = (_Float16)f1.x; ah[5] = (_Float16)f1.y;
                ah[6] = (_Float16)f1.z; ah[7] = (_Float16)f1.w;
            } else {
                ah = *(const half8*)&Ah[row * 32 + ((quad + row) & 3) * 8];
            }
        }
        half8 bh[4];
#pragma unroll
        for (int ni = 0; ni < 4; ++ni) {
            const int row = ni * 16 + l15;
            bh[ni] = *(const half8*)&Bb[row * 32 + ((quad + row) & 3) * 8];
        }
        // ---- MFMAs ----
#pragma unroll
        for (int ni = 0; ni < 4; ++ni)
            acc[ni] = MFMA16F(ah, bh[ni], acc[ni]);
        __syncthreads();
        cur ^= 1;
    }

    // ---- epilogue ----
#pragma unroll
    for (int ni = 0; ni < 4; ++ni) {
        const int n = n0 + ni * 16 + l15;
#pragma unroll
        for (int r = 0; r < 4; ++r) {
            const int m = m0 + 16 * w + quad * 4 + r;
            const float v = acc[ni][r];
            if (OUTMODE == 0) {
                outF[(size_t)m * 512 + n] = v * P_ISCALE;
            } else if (OUTMODE == 1) {
                ((_Float16*)outH)[(size_t)m * 512 + n] = (_Float16)v;
            } else {
                const int b = m >> 10, t = m & 1023, hh = n >> 6, d = n & 63;
                ((_Float16*)outH)[((size_t)(b * 8 + hh) * 64 + d) * 1024 + t] =
                    (_Float16)v;
            }
        }
    }
    if (OUTMODE == 1) {
        // Fused per-head squared norms from the f16-ROUNDED values (must
        // match what flash reads for exact ||q~-k~||^2 expansion).
        // head index = nt (64-col n-panel = one head).
#pragma unroll
        for (int r = 0; r < 4; ++r) {
            float s2 = 0.f;
#pragma unroll
            for (int ni = 0; ni < 4; ++ni) {
                const float rv = (float)(_Float16)acc[ni][r];
                s2 = fmaf(rv, rv, s2);
            }
#pragma unroll
            for (int off = 1; off < 16; off <<= 1) s2 += __shfl_xor(s2, off);
            if (l15 == 0) {
                const int m = m0 + 16 * w + quad * 4 + r;
                normOut[(size_t)((m >> 10) * 8 + nt) * 1024 + (m & 1023)] = s2;
            }
        }
    }
}

// ---------------------------------------------------------------------------
// Fused flash (R11, unchanged): block = (z, 64 q-rows), 4 waves;
// gid = qt*64+z so gid%8==h (same z -> same XCD: K/V L2-resident).
// Per 64-col tile: stage K/V^T f16 (2x8KB, swizzled) -> barrier -> QK
// 1-pass f16 MFMA -> exp -> S store + P strip (f16, x2^60) -> SV f16 MFMA
// -> barrier.  25.2KB LDS -> 4+ blocks/CU.  attn stored f16 @ 2^60 scale.
// ---------------------------------------------------------------------------
__global__ __launch_bounds__(256) void flash_rbf(
    const ushort_t* __restrict__ qh, const ushort_t* __restrict__ kh,
    const ushort_t* __restrict__ vhT, const float* __restrict__ q2,
    const float* __restrict__ k2, float* __restrict__ S,
    ushort_t* __restrict__ attn)
{
    __shared__ __align__(16) ushort_t sK[64 * 64];
    __shared__ __align__(16) ushort_t sV[64 * 64];
    __shared__ __align__(16) ushort_t P [64 * 72];

    const int tid = threadIdx.x;
    const int w = tid >> 6, lane = tid & 63;
    const int l15 = lane & 15, quad = lane >> 4;
    const int gid = blockIdx.x;
    const int z = gid & 63, qt = gid >> 6;
    const int b = z >> 3, h = z & 7;
    const int q0 = qt * 64;

    // Q fragments (f16 registers, whole block).
    const size_t qrow = (size_t)(b * 1024 + q0 + 16 * w + l15) * 512 + h * 64 + quad * 8;
    half8 aq0 = *(const half8*)((const _Float16*)qh + qrow);
    half8 aq1 = *(const half8*)((const _Float16*)qh + qrow + 32);

    float q2v[4];
#pragma unroll
    for (int r = 0; r < 4; ++r)
        q2v[r] = q2[(size_t)z * 1024 + q0 + 16 * w + quad * 4 + r];

    floatx4 oacc[4];
#pragma unroll
    for (int i = 0; i < 4; ++i) oacc[i] = (floatx4){0.f, 0.f, 0.f, 0.f};

    const size_t Sz = (size_t)z << 20;

    for (int ct = 0; ct < 16; ++ct) {
        const int col0 = ct * 64;

        // ---- stage K + V^T f16 tiles (rows of 8 chunks, swizzled) ----
#pragma unroll
        for (int t = 0; t < 2; ++t) {
            const int c = (w * 2 + t) * 64 + lane;
            const int row = c >> 3, slot = c & 7, dch = (slot - row) & 7;
            const size_t ke = (size_t)(b * 1024 + col0 + row) * 512 + h * 64 + dch * 8;
            const size_t ve = ((size_t)z * 64 + row) * 1024 + col0 + dch * 8;
            gl_lds16(kh + ke,  (char*)sK + (size_t)(w * 2 + t) * 1024);
            gl_lds16(vhT + ve, (char*)sV + (size_t)(w * 2 + t) * 1024);
        }
        float k2v[4];
#pragma unroll
        for (int j = 0; j < 4; ++j)
            k2v[j] = k2[(size_t)z * 1024 + col0 + j * 16 + l15];
        __syncthreads();

        // ---- QK^T, 1-pass f16 ----
        floatx4 s[4];
#pragma unroll
        for (int j = 0; j < 4; ++j) {
            const int row = j * 16 + l15;
            const int base = row * 64;
            half8 k0 = *(const half8*)&sK[base + ((quad + row) & 7) * 8];
            half8 k1 = *(const half8*)&sK[base + ((quad + 4 + row) & 7) * 8];
            s[j] = (floatx4){0.f, 0.f, 0.f, 0.f};
            s[j] = MFMA16F(aq0, k0, s[j]);
            s[j] = MFMA16F(aq1, k1, s[j]);
        }

        // ---- V fragments (f16) ----
        half8 gv0[4], gv1[4];
#pragma unroll
        for (int j2 = 0; j2 < 4; ++j2) {
            const int row = j2 * 16 + l15;
            const int base = row * 64;
            gv0[j2] = *(const half8*)&sV[base + ((quad + row) & 7) * 8];
            gv1[j2] = *(const half8*)&sV[base + ((quad + 4 + row) & 7) * 8];
        }

        // ---- exp, S store, P pack (f16, scaled 2^60) ----
#pragma unroll
        for (int j = 0; j < 4; ++j) {
#pragma unroll
            for (int r = 0; r < 4; ++r) {
                const float val = __expf(2.f * s[j][r] - q2v[r] - k2v[j]);
                const int row = q0 + 16 * w + quad * 4 + r;
                S[Sz + (size_t)row * 1024 + col0 + j * 16 + l15] = val;
                P[(16 * w + quad * 4 + r) * 72 + j * 16 + l15] =
                    __builtin_bit_cast(ushort_t, (_Float16)(val * P_SCALE));
            }
        }

        // ---- P readback (A-layout, wave-local) + S@V, f16 ----
        half8 pf0 = *(const half8*)&P[(16 * w + l15) * 72 + quad * 8];
        half8 pf1 = *(const half8*)&P[(16 * w + l15) * 72 + 32 + quad * 8];
#pragma unroll
        for (int j2 = 0; j2 < 4; ++j2) {
            oacc[j2] = MFMA16F(pf0, gv0[j2], oacc[j2]);
            oacc[j2] = MFMA16F(pf1, gv1[j2], oacc[j2]);
        }
        __syncthreads();
    }

    // attn stored f16 at the 2^60 scale (out GEMM applies 2^-60).
#pragma unroll
    for (int j2 = 0; j2 < 4; ++j2)
#pragma unroll
        for (int r = 0; r < 4; ++r) {
            const int row = q0 + 16 * w + quad * 4 + r;
            ((_Float16*)attn)[(size_t)(b * 1024 + row) * 512 + h * 64 + j2 * 16 + l15] =
                (_Float16)oacc[j2][r];
        }
}

extern "C" void kernel_launch(void* const* d_in, const int* in_sizes, int n_in,
                              void* d_out, int out_size, void* d_ws, size_t ws_size,
                              hipStream_t stream)
{
    const float* query = (const float*)d_in[0];
    const float* key   = (const float*)d_in[1];
    const float* value = (const float*)d_in[2];
    const float* Wq    = (const float*)d_in[3];
    const float* Wk    = (const float*)d_in[4];
    const float* Wv    = (const float*)d_in[5];
    const float* Wo    = (const float*)d_in[6];

    float* out  = (float*)d_out;
    float* Sout = out + (size_t)8192 * 512;

    const size_t NE = (size_t)8192 * 512;
    ushort_t* qh_f16   = (ushort_t*)d_ws;
    ushort_t* kh_f16   = qh_f16 + NE;
    ushort_t* vhT      = kh_f16 + NE;
    ushort_t* attn_f16 = vhT + NE;
    ushort_t* WqT      = attn_f16 + NE;
    ushort_t* WkT      = WqT + 262144;
    ushort_t* WvT      = WkT + 262144;
    ushort_t* WoT      = WvT + 262144;
    float*    q2       = (float*)(WoT + 262144);
    float*    k2       = q2 + 65536;

    wt_cvt<<<dim3(64, 4), 256, 0, stream>>>(Wq, Wk, Wv, Wo, WqT, WkT, WvT, WoT);

    gemm_f16<true, 1><<<1024, 256, 0, stream>>>(
        query, WqT, nullptr, qh_f16, q2);
    gemm_f16<true, 1><<<1024, 256, 0, stream>>>(
        key, WkT, nullptr, kh_f16, k2);
    gemm_f16<true, 2><<<1024, 256, 0, stream>>>(
        value, WvT, nullptr, vhT, nullptr);

    flash_rbf<<<1024, 256, 0, stream>>>(qh_f16, kh_f16, vhT, q2, k2,
                                        Sout, attn_f16);

    gemm_f16<false, 0><<<1024, 256, 0, stream>>>(
        attn_f16, WoT, out, nullptr, nullptr);
}